// Round 16
// baseline (71.036 us; speedup 1.0000x reference)
//
#include <hip/hip_runtime.h>
#include <hip/hip_bf16.h>
#include <stdint.h>

#define TOKENS 4096
#define DIN 1024
#define DOUT 1024
#define RANK 8
#define BM 128
#define BN 64
#define BK 64
#define TPB 4            // tokens per inter-block
#define NBI (TOKENS / TPB)   // 1024 inter blocks

typedef __attribute__((ext_vector_type(4))) float f32x4;
typedef __attribute__((ext_vector_type(8))) short short8;

__device__ __forceinline__ unsigned short f2bf(float f) {
    union { float f; unsigned u; } v; v.f = f;
    unsigned r = v.u + 0x7FFFu + ((v.u >> 16) & 1u);
    return (unsigned short)(r >> 16);
}

__device__ __forceinline__ float dot4(float4 a, float4 b) {
    return a.x * b.x + a.y * b.y + a.z * b.z + a.w * b.w;
}

// Blocks [0,NBI): 4 tokens/block. Per half-token quantum, 4 B-rows (16KB) +
// x (4KB) are DMA-staged into dbuf LDS via global_load_lds — in-flight bytes
// live in the LDS-DMA queue, not VGPRs (Little's-law fix: ~60-80KB/CU
// outstanding vs ~5KB for the register version). Each wave dots ONE row from
// LDS (lane-contiguous ds_read_b128, conflict-free) + shfl reduce.
// Blocks [NBI, NBI+256): W fp32->bf16.
__global__ __launch_bounds__(256) void k_inter_cvt(const float* __restrict__ x,
                                                   const float* __restrict__ Bp,
                                                   const float* __restrict__ W,
                                                   float* __restrict__ inter,
                                                   ushort* __restrict__ xb,
                                                   ushort* __restrict__ Wb) {
    const int bid = blockIdx.x;
    const int tid = threadIdx.x;

    if (bid >= NBI) {
        const int b2 = bid - NBI;
        const float4* w4 = (const float4*)(W + (size_t)b2 * 4096);
        ushort4* o4 = (ushort4*)(Wb + (size_t)b2 * 4096);
#pragma unroll
        for (int j = 0; j < 4; ++j) {
            float4 v = w4[j * 256 + tid];
            ushort4 u;
            u.x = f2bf(v.x); u.y = f2bf(v.y); u.z = f2bf(v.z); u.w = f2bf(v.w);
            o4[j * 256 + tid] = u;
        }
        return;
    }

    __shared__ float bls[2][4 * 1024];   // 2 x 16 KB: 4 B-rows
    __shared__ float xls[2][1024];       // 2 x 4 KB: x row

    const int lane = tid & 63, wid = tid >> 6;
    const int T0 = bid * TPB;

    auto stageB = [&](int buf, int t, int h) {
#pragma unroll
        for (int s = 0; s < 4; ++s) {
            const float* g = Bp + ((size_t)t * RANK + h * 4) * DIN + s * 1024 + tid * 4;
            __builtin_amdgcn_global_load_lds(
                (const __attribute__((address_space(1))) void*)g,
                (__attribute__((address_space(3))) void*)(&bls[buf][s * 1024 + tid * 4]),
                16, 0, 0);
        }
    };
    auto stageX = [&](int buf, int t) {
        const float* g = x + (size_t)t * DIN + tid * 4;
        __builtin_amdgcn_global_load_lds(
            (const __attribute__((address_space(1))) void*)g,
            (__attribute__((address_space(3))) void*)(&xls[buf][tid * 4]), 16, 0, 0);
    };

    // Prologue: token 0's x + first half-B.
    stageX(0, T0);
    stageB(0, T0, 0);

#pragma unroll
    for (int q = 0; q < 2 * TPB; ++q) {
        const int tl = q >> 1, h = q & 1;
        const int t = T0 + tl;
        const int bb = q & 1, xbuf = tl & 1;

        // Prefetch next quantum (writes the OPPOSITE buffers — safe).
        if (q + 1 < 2 * TPB) stageB((q + 1) & 1, T0 + ((q + 1) >> 1), (q + 1) & 1);
        if (h == 1 && tl + 1 < TPB) stageX((tl + 1) & 1, t + 1);

        asm volatile("s_waitcnt vmcnt(0)" ::: "memory");
        __builtin_amdgcn_s_barrier();

        // Wave wid dots row (h*4 + wid) against x, both from LDS.
        const float* br = &bls[bb][wid * 1024];
        const float* xr = &xls[xbuf][0];
        float s = 0.f;
#pragma unroll
        for (int j = 0; j < 4; ++j) {
            float4 bv = *(const float4*)(br + j * 256 + lane * 4);
            float4 xv = *(const float4*)(xr + j * 256 + lane * 4);
            s += dot4(bv, xv);
        }
#pragma unroll
        for (int off = 32; off > 0; off >>= 1)
            s += __shfl_xor(s, off, 64);
        if (lane == 0) inter[(size_t)t * RANK + h * 4 + wid] = s;

        // Once per token: xb conversion, wave wid covers quarter wid.
        if (h == 0) {
            float4 v = *(const float4*)(xr + wid * 256 + lane * 4);
            ushort4 u;
            u.x = f2bf(v.x); u.y = f2bf(v.y); u.z = f2bf(v.z); u.w = f2bf(v.w);
            *(ushort4*)(xb + (size_t)t * DIN + wid * 256 + lane * 4) = u;
        }

        __builtin_amdgcn_s_barrier();   // protect read buffers from next stage
    }
}

// out[m,o] = bias[o] + Xb@Wb^T (bf16 MFMA) + sum_r inter[m,r]*A[m,o,r]
// UNCHANGED from R14/R15 (counted-vmcnt order-pinned pipeline + T2 swizzle).
__global__ __launch_bounds__(256, 2) void k_gemm_fused(const ushort* __restrict__ Xb,
                                                       const ushort* __restrict__ Wb,
                                                       const float* __restrict__ bias,
                                                       const float* __restrict__ inter,
                                                       const float* __restrict__ Ap,
                                                       float* __restrict__ out) {
    __shared__ ushort As[2][BM * BK];   // 2 x 16 KB
    __shared__ ushort Bs[2][BN * BK];   // 2 x 8 KB
    __shared__ float sInter[BM * 8];    // 4 KB
    __shared__ float sBias[BN];

    const int tid = threadIdx.x;
    const int lane = tid & 63, wave = tid >> 6;
    const int wm = wave >> 1, wn = wave & 1;

    const int bid = blockIdx.x;
    const int swz = (bid & 7) * 64 + (bid >> 3);
    const int M0 = (swz >> 4) * BM;
    const int N0 = (swz & 15) * BN;

    const int col16 = lane & 15;
    const int kg = lane >> 4;
    const int c8 = col16 & 7;

    ((float4*)sInter)[tid] = ((const float4*)(inter + (size_t)M0 * RANK))[tid];
    if (tid < 16) ((float4*)sBias)[tid] = ((const float4*)(bias + N0))[tid];

    const float* Abase = Ap + ((size_t)(M0 + wm * 64 + kg * 4) * DOUT +
                               (N0 + wn * 32 + col16)) * RANK;

    auto stage = [&](int b, int kt) {
#pragma unroll
        for (int st = 0; st < 4; ++st) {
            int flat = st * 256 + tid;
            int row = flat >> 3, ch = flat & 7;
            int chs = ch ^ (row & 7);
            const ushort* g = Xb + (size_t)(M0 + row) * DIN + kt + chs * 8;
            __builtin_amdgcn_global_load_lds(
                (const __attribute__((address_space(1))) void*)g,
                (__attribute__((address_space(3))) void*)(&As[b][flat * 8]), 16, 0, 0);
        }
#pragma unroll
        for (int st = 0; st < 2; ++st) {
            int flat = st * 256 + tid;
            int row = flat >> 3, ch = flat & 7;
            int chs = ch ^ (row & 7);
            const ushort* g = Wb + (size_t)(N0 + row) * DIN + kt + chs * 8;
            __builtin_amdgcn_global_load_lds(
                (const __attribute__((address_space(1))) void*)g,
                (__attribute__((address_space(3))) void*)(&Bs[b][flat * 8]), 16, 0, 0);
        }
    };

    auto aptr = [&](int e) {
        const int nf = e >> 3, mf = (e >> 1) & 3, rg0 = (e & 1) * 2;
        return Abase + ((size_t)(mf * 16 + rg0) * DOUT + nf * 16) * RANK;
    };

    float4 areg[2][4];

    {
        const float* Ae0 = aptr(0);
        areg[0][0] = ((const float4*)Ae0)[0];
        areg[0][1] = ((const float4*)Ae0)[1];
        areg[0][2] = ((const float4*)(Ae0 + (size_t)DOUT * RANK))[0];
        areg[0][3] = ((const float4*)(Ae0 + (size_t)DOUT * RANK))[1];
    }
    __builtin_amdgcn_sched_barrier(0);
    stage(0, 0);

    f32x4 acc[4][2] = {};

#pragma unroll
    for (int t = 0; t < 16; ++t) {
        const int cur = t & 1;

        if (t < 15) {
            const float* Ae0 = aptr(t + 1);
            areg[cur ^ 1][0] = ((const float4*)Ae0)[0];
            areg[cur ^ 1][1] = ((const float4*)Ae0)[1];
            areg[cur ^ 1][2] = ((const float4*)(Ae0 + (size_t)DOUT * RANK))[0];
            areg[cur ^ 1][3] = ((const float4*)(Ae0 + (size_t)DOUT * RANK))[1];
            __builtin_amdgcn_sched_barrier(0);
            stage(cur ^ 1, (t + 1) * BK);
        }

        if (t == 0) {
            asm volatile("s_waitcnt vmcnt(10) lgkmcnt(0)" ::: "memory");
        } else if (t < 15) {
            asm volatile("s_waitcnt vmcnt(10)" ::: "memory");
        } else {
            asm volatile("s_waitcnt vmcnt(0)" ::: "memory");
        }
        __builtin_amdgcn_s_barrier();

#pragma unroll
        for (int ks = 0; ks < 2; ++ks) {
            short8 a[4], b[2];
#pragma unroll
            for (int m4 = 0; m4 < 4; ++m4) {
                const int chs = (ks * 4 + kg) ^ c8;
                a[m4] = *(const short8*)(&As[cur][(wm * 64 + m4 * 16 + col16) * BK + chs * 8]);
            }
#pragma unroll
            for (int n2 = 0; n2 < 2; ++n2) {
                const int chs = (ks * 4 + kg) ^ c8;
                b[n2] = *(const short8*)(&Bs[cur][(wn * 32 + n2 * 16 + col16) * BK + chs * 8]);
            }
#pragma unroll
            for (int m4 = 0; m4 < 4; ++m4)
#pragma unroll
                for (int n2 = 0; n2 < 2; ++n2)
                    acc[m4][n2] = __builtin_amdgcn_mfma_f32_16x16x32_bf16(
                        a[m4], b[n2], acc[m4][n2], 0, 0, 0);
        }

        {
            const int nf = t >> 3, mf = (t >> 1) & 3, rg0 = (t & 1) * 2;
            const int mloc0 = wm * 64 + mf * 16 + kg * 4 + rg0;
            const float4* iv0 = (const float4*)(sInter + mloc0 * 8);
            const float4* iv1 = (const float4*)(sInter + (mloc0 + 1) * 8);
            float4 i00 = iv0[0], i01 = iv0[1], i10 = iv1[0], i11 = iv1[1];
            float4 a00 = areg[cur][0], a01 = areg[cur][1];
            float4 a10 = areg[cur][2], a11 = areg[cur][3];
            float d0 = dot4(a00, i00) + dot4(a01, i01);
            float d1 = dot4(a10, i10) + dot4(a11, i11);
            acc[mf][nf][rg0] += d0;
            acc[mf][nf][rg0 + 1] += d1;
        }

        __builtin_amdgcn_s_barrier();
    }

#pragma unroll
    for (int nf = 0; nf < 2; ++nf) {
        const int oc = wn * 32 + nf * 16 + col16;
        const int o = N0 + oc;
        const float bb = sBias[oc];
#pragma unroll
        for (int mf = 0; mf < 4; ++mf) {
#pragma unroll
            for (int rg = 0; rg < 4; ++rg) {
                const int m = M0 + wm * 64 + mf * 16 + kg * 4 + rg;
                out[(size_t)m * DOUT + o] = acc[mf][nf][rg] + bb;
            }
        }
    }
}

extern "C" void kernel_launch(void* const* d_in, const int* in_sizes, int n_in,
                              void* d_out, int out_size, void* d_ws, size_t ws_size,
                              hipStream_t stream) {
    const float* x    = (const float*)d_in[0];
    const float* Ap   = (const float*)d_in[1];
    const float* Bp   = (const float*)d_in[2];
    const float* W    = (const float*)d_in[3];
    const float* bias = (const float*)d_in[4];
    float* out = (float*)d_out;

    // ws: xb (8 MB) | Wb (2 MB) | inter (128 KB)
    ushort* xb = (ushort*)d_ws;
    ushort* Wb = xb + (size_t)TOKENS * DIN;
    float* inter = (float*)(Wb + (size_t)DOUT * DIN);

    hipLaunchKernelGGL(k_inter_cvt, dim3(NBI + 256), dim3(256), 0, stream,
                       x, Bp, W, inter, xb, Wb);
    hipLaunchKernelGGL(k_gemm_fused, dim3((TOKENS / BM) * (DOUT / BN)), dim3(256), 0, stream,
                       xb, Wb, bias, inter, Ap, out);
}